// Round 1
// baseline (425.035 us; speedup 1.0000x reference)
//
#include <hip/hip_runtime.h>
#include <hip/hip_bf16.h>

constexpr int TTOK  = 16384;   // B*S = 8*2048
constexpr int DDIM  = 512;
constexpr int FFDIM = 2048;
constexpr int NEXP  = 8;
constexpr int GB_TOK = 64;             // tokens per gate/scatter block
constexpr int NGB    = TTOK / GB_TOK;  // 256

typedef __attribute__((ext_vector_type(8))) short short8_t;
typedef __attribute__((ext_vector_type(4))) float f32x4_t;

__device__ __forceinline__ unsigned short f2bf(float f) {
    union { float f; unsigned u; } v; v.f = f;
    return (unsigned short)((v.u + 0x7fffu + ((v.u >> 16) & 1u)) >> 16);  // RNE
}

__device__ __forceinline__ void gl_lds16(const void* g, void* l) {
    __builtin_amdgcn_global_load_lds(
        (const __attribute__((address_space(1))) void*)g,
        (__attribute__((address_space(3))) void*)l,
        16, 0, 0);
}

// ---------------- transpose + fp32->bf16 cast:  src [E][R][C] f32 -> dst [E][C][R] bf16
__global__ __launch_bounds__(256) void transpose_cvt(const float* __restrict__ src,
                                                     unsigned short* __restrict__ dst,
                                                     int R, int C) {
    __shared__ float tile[32][33];
    int e = blockIdx.z;
    int c0 = blockIdx.x * 32;
    int r0 = blockIdx.y * 32;
    const float* s = src + (size_t)e * R * C;
    unsigned short* d = dst + (size_t)e * R * C;
    int tx = threadIdx.x, ty = threadIdx.y;   // 32 x 8
    #pragma unroll
    for (int i = 0; i < 4; i++)
        tile[ty + 8 * i][tx] = s[(size_t)(r0 + ty + 8 * i) * C + c0 + tx];
    __syncthreads();
    #pragma unroll
    for (int i = 0; i < 4; i++)
        d[(size_t)(c0 + ty + 8 * i) * R + r0 + tx] = f2bf(tile[tx][ty + 8 * i]);
}

// ---------------- gating: logits (f64 accum), softmax-max prob, argmax route, per-block histogram
__global__ __launch_bounds__(256) void gate_kernel(const float* __restrict__ x,
                                                   const float* __restrict__ Wg,
                                                   const float* __restrict__ bg,
                                                   int* __restrict__ route,
                                                   float* __restrict__ pmax,
                                                   int* __restrict__ blockCounts) {
    __shared__ float wg[DDIM * NEXP];   // 16 KB, layout [d][e]
    __shared__ int cnt[NEXP];
    int tid = threadIdx.x;
    for (int i = tid; i < DDIM * NEXP; i += 256) wg[i] = Wg[i];
    if (tid < NEXP) cnt[tid] = 0;
    __syncthreads();
    int wave = tid >> 6, lane = tid & 63;
    int tbase = blockIdx.x * GB_TOK + wave * 16;
    for (int it = 0; it < 16; it++) {
        int t = tbase + it;
        double acc[NEXP];
        #pragma unroll
        for (int e = 0; e < NEXP; e++) acc[e] = 0.0;
        const float* xr = x + (size_t)t * DDIM + lane * 8;
        #pragma unroll
        for (int jj = 0; jj < 8; jj++) {
            double xv = (double)xr[jj];
            const float* wr = &wg[(lane * 8 + jj) * NEXP];
            #pragma unroll
            for (int e = 0; e < NEXP; e++) acc[e] += xv * (double)wr[e];
        }
        #pragma unroll
        for (int off = 32; off > 0; off >>= 1) {
            #pragma unroll
            for (int e = 0; e < NEXP; e++) acc[e] += __shfl_down(acc[e], off);
        }
        if (lane == 0) {
            double l[NEXP];
            #pragma unroll
            for (int e = 0; e < NEXP; e++) l[e] = acc[e] + (double)bg[e];
            int r = 0; double lm = l[0];
            #pragma unroll
            for (int e = 1; e < NEXP; e++) if (l[e] > lm) { lm = l[e]; r = e; }
            double s = 0.0;
            #pragma unroll
            for (int e = 0; e < NEXP; e++) s += exp(l[e] - lm);
            route[t] = r;
            pmax[t] = (float)(1.0 / s);
            atomicAdd(&cnt[r], 1);
        }
    }
    __syncthreads();
    if (tid < NEXP) blockCounts[blockIdx.x * NEXP + tid] = cnt[tid];
}

// ---------------- single-block scan over [NGB][NEXP] counts -> stable counting-sort offsets
__global__ __launch_bounds__(NGB) void scan_kernel(const int* __restrict__ blockCounts,
                                                   int* __restrict__ blockOffsets,
                                                   int* __restrict__ segPrefix) {
    __shared__ int sc[NGB][NEXP];
    __shared__ int base[NEXP + 1];
    int b = threadIdx.x;
    int c[NEXP];
    #pragma unroll
    for (int e = 0; e < NEXP; e++) { c[e] = blockCounts[b * NEXP + e]; sc[b][e] = c[e]; }
    __syncthreads();
    for (int off = 1; off < NGB; off <<= 1) {
        int t[NEXP];
        if (b >= off) {
            #pragma unroll
            for (int e = 0; e < NEXP; e++) t[e] = sc[b - off][e];
        }
        __syncthreads();
        if (b >= off) {
            #pragma unroll
            for (int e = 0; e < NEXP; e++) sc[b][e] += t[e];
        }
        __syncthreads();
    }
    if (b == 0) {
        int s = 0;
        #pragma unroll
        for (int e = 0; e < NEXP; e++) { base[e] = s; s += sc[NGB - 1][e]; }
        base[NEXP] = s;
        for (int e = 0; e <= NEXP; e++) segPrefix[e] = base[e];
    }
    __syncthreads();
    #pragma unroll
    for (int e = 0; e < NEXP; e++)
        blockOffsets[b * NEXP + e] = base[e] + sc[b][e] - c[e];
}

// ---------------- scatter: Xs[dst(t)] = bf16(x[t] * pmax[t]), expert-sorted stable order
__global__ __launch_bounds__(256) void scatter_kernel(const float* __restrict__ x,
                                                      const int* __restrict__ route,
                                                      const float* __restrict__ pmax,
                                                      const int* __restrict__ blockOffsets,
                                                      unsigned short* __restrict__ Xs) {
    __shared__ int dstL[GB_TOK];
    __shared__ float pmL[GB_TOK];
    int tid = threadIdx.x;
    int bb = blockIdx.x;
    if (tid < 64) {
        int t = bb * GB_TOK + tid;
        int r = route[t];
        unsigned long long ltmask = (tid == 0) ? 0ull : ((~0ull) >> (64 - tid));
        int rank = 0;
        #pragma unroll
        for (int e = 0; e < NEXP; e++) {
            unsigned long long m = __ballot(r == e);
            if (r == e) rank = __popcll(m & ltmask);
        }
        dstL[tid] = blockOffsets[bb * NEXP + r] + rank;
        pmL[tid] = pmax[t];
    }
    __syncthreads();
    int wave = tid >> 6, lane = tid & 63;
    for (int rr = 0; rr < 16; rr++) {
        int rowl = wave * 16 + rr;
        int t = bb * GB_TOK + rowl;
        float pm = pmL[rowl];
        const float4* xr = (const float4*)(x + (size_t)t * DDIM) + lane * 2;
        float4 a = xr[0], b = xr[1];
        union { short8_t v; unsigned short s[8]; } o;
        o.s[0] = f2bf(a.x * pm); o.s[1] = f2bf(a.y * pm);
        o.s[2] = f2bf(a.z * pm); o.s[3] = f2bf(a.w * pm);
        o.s[4] = f2bf(b.x * pm); o.s[5] = f2bf(b.y * pm);
        o.s[6] = f2bf(b.z * pm); o.s[7] = f2bf(b.w * pm);
        *(short8_t*)(Xs + (size_t)dstL[rowl] * DDIM + lane * 8) = o.v;
    }
}

// ---------------- segmented GEMM: C[seg] = act(A[seg] @ Bt[e]^T + bias[e])
// A [TTOK][K] bf16 row-major, Bt [E][N][K] bf16 row-major, 128x128x32 tiles, 4 waves.
template <bool RELU, typename OutT>
__global__ __launch_bounds__(256) void gemm_seg(const unsigned short* __restrict__ A,
                                                const unsigned short* __restrict__ Bt,
                                                const float* __restrict__ bias,
                                                OutT* __restrict__ C,
                                                const int* __restrict__ segPrefix,
                                                int K, int N) {
    int e = blockIdx.z;
    int seg0 = segPrefix[e], seg1 = segPrefix[e + 1];
    int m0 = seg0 + blockIdx.x * 128;
    if (m0 >= seg1) return;
    int n0 = blockIdx.y * 128;

    __shared__ unsigned short As[128 * 32];  // 8 KB, [m][k] linear (global_load_lds order)
    __shared__ unsigned short Bs[128 * 32];  // 8 KB, [n][k] linear

    int tid = threadIdx.x, wave = tid >> 6, lane = tid & 63;
    const unsigned short* Bte = Bt + (size_t)e * N * K;

    int srow = lane >> 2;          // staging row within 16-row region
    int scol = (lane & 3) * 8;     // staging k-offset (8 bf16 = 16 B)

    f32x4_t acc[4][4];
    #pragma unroll
    for (int i = 0; i < 4; i++)
        #pragma unroll
        for (int j = 0; j < 4; j++) acc[i][j] = (f32x4_t){0.f, 0.f, 0.f, 0.f};

    int wm = (wave & 1) * 64;
    int wn = (wave >> 1) * 64;
    int frow = lane & 15;
    int fk = (lane >> 4) * 8;

    for (int kc = 0; kc < K; kc += 32) {
        #pragma unroll
        for (int i = 0; i < 2; i++) {
            int reg = wave * 2 + i;                 // 16-row region 0..7
            int arow = m0 + reg * 16 + srow;
            arow = arow < TTOK ? arow : TTOK - 1;   // clamp: masked at store
            gl_lds16(A + (size_t)arow * K + kc + scol, &As[reg * 512]);
            int brow = n0 + reg * 16 + srow;
            gl_lds16(Bte + (size_t)brow * K + kc + scol, &Bs[reg * 512]);
        }
        __syncthreads();   // drains vmcnt -> LDS visible
        short8_t af[4], bf[4];
        #pragma unroll
        for (int i = 0; i < 4; i++)
            af[i] = *(const short8_t*)&As[(wm + i * 16 + frow) * 32 + fk];
        #pragma unroll
        for (int j = 0; j < 4; j++)
            bf[j] = *(const short8_t*)&Bs[(wn + j * 16 + frow) * 32 + fk];
        #pragma unroll
        for (int i = 0; i < 4; i++)
            #pragma unroll
            for (int j = 0; j < 4; j++)
                acc[i][j] = __builtin_amdgcn_mfma_f32_16x16x32_bf16(af[i], bf[j], acc[i][j], 0, 0, 0);
        __syncthreads();   // all waves done reading before next overwrite
    }

    int quad = lane >> 4;
    int colb = lane & 15;
    #pragma unroll
    for (int i = 0; i < 4; i++) {
        #pragma unroll
        for (int j = 0; j < 4; j++) {
            int col = n0 + wn + j * 16 + colb;
            float bv = bias[(size_t)e * N + col];
            #pragma unroll
            for (int r = 0; r < 4; r++) {
                int row = m0 + wm + i * 16 + quad * 4 + r;
                if (row < seg1) {
                    float v = acc[i][j][r] + bv;
                    if (RELU) v = fmaxf(v, 0.0f);
                    if constexpr (sizeof(OutT) == 2) {
                        C[(size_t)row * N + col] = (OutT)f2bf(v);
                    } else {
                        C[(size_t)row * N + col] = v;
                    }
                }
            }
        }
    }
}

extern "C" void kernel_launch(void* const* d_in, const int* in_sizes, int n_in,
                              void* d_out, int out_size, void* d_ws, size_t ws_size,
                              hipStream_t stream) {
    const float* x  = (const float*)d_in[0];
    const float* Wg = (const float*)d_in[1];
    const float* bg = (const float*)d_in[2];
    const float* W1 = (const float*)d_in[3];
    const float* b1 = (const float*)d_in[4];
    const float* W2 = (const float*)d_in[5];
    const float* b2 = (const float*)d_in[6];
    float* out = (float*)d_out;

    char* ws = (char*)d_ws;
    size_t off = 0;
    auto alloc = [&](size_t bytes) -> char* {
        char* p = ws + off;
        off += (bytes + 255) & ~(size_t)255;
        return p;
    };
    unsigned short* W1T = (unsigned short*)alloc((size_t)NEXP * DDIM * FFDIM * 2);  // [E][FF][D]
    unsigned short* W2T = (unsigned short*)alloc((size_t)NEXP * DDIM * FFDIM * 2);  // [E][D][FF]
    unsigned short* Xs  = (unsigned short*)alloc((size_t)TTOK * DDIM * 2);          // sorted tokens
    unsigned short* H   = (unsigned short*)alloc((size_t)TTOK * FFDIM * 2);         // hidden
    int*   route        = (int*)alloc((size_t)TTOK * 4);
    float* pmaxArr      = (float*)alloc((size_t)TTOK * 4);
    int*   blockCounts  = (int*)alloc((size_t)NGB * NEXP * 4);
    int*   blockOffsets = (int*)alloc((size_t)NGB * NEXP * 4);
    int*   segPrefix    = (int*)alloc((size_t)(NEXP + 1) * 4);

    // 1-2: weight transpose + bf16 cast
    transpose_cvt<<<dim3(FFDIM / 32, DDIM / 32, NEXP), dim3(32, 8), 0, stream>>>(W1, W1T, DDIM, FFDIM);
    transpose_cvt<<<dim3(DDIM / 32, FFDIM / 32, NEXP), dim3(32, 8), 0, stream>>>(W2, W2T, FFDIM, DDIM);
    // 3: gating
    gate_kernel<<<NGB, 256, 0, stream>>>(x, Wg, bg, route, pmaxArr, blockCounts);
    // 4: scan -> stable sort offsets
    scan_kernel<<<1, NGB, 0, stream>>>(blockCounts, blockOffsets, segPrefix);
    // 5: permute + scale + cast tokens
    scatter_kernel<<<NGB, 256, 0, stream>>>(x, route, pmaxArr, blockOffsets, Xs);
    // 6: H = relu(Xs @ W1[e] + b1[e])  (bf16)
    gemm_seg<true, unsigned short><<<dim3(TTOK / 128, FFDIM / 128, NEXP), 256, 0, stream>>>(
        Xs, W1T, b1, H, segPrefix, DDIM, FFDIM);
    // 7: out = H @ W2[e] + b2[e]  (fp32, already in sorted order)
    gemm_seg<false, float><<<dim3(TTOK / 128, DDIM / 128, NEXP), 256, 0, stream>>>(
        H, W2T, b2, out, segPrefix, FFDIM, DDIM);
}

// Round 2
// 329.735 us; speedup vs baseline: 1.2890x; 1.2890x over previous
//
#include <hip/hip_runtime.h>
#include <hip/hip_bf16.h>

constexpr int TTOK  = 16384;   // B*S = 8*2048
constexpr int DDIM  = 512;
constexpr int FFDIM = 2048;
constexpr int NEXP  = 8;
constexpr int GB_TOK = 64;             // tokens per gate/scatter block
constexpr int NGB    = TTOK / GB_TOK;  // 256
constexpr int MAXTILES = TTOK / 128 + NEXP;  // 136: worst-case M-tiles over all experts

typedef __attribute__((ext_vector_type(8))) short short8_t;
typedef __attribute__((ext_vector_type(4))) float f32x4_t;

__device__ __forceinline__ unsigned short f2bf(float f) {
    union { float f; unsigned u; } v; v.f = f;
    return (unsigned short)((v.u + 0x7fffu + ((v.u >> 16) & 1u)) >> 16);  // RNE
}

__device__ __forceinline__ void gl_lds16(const void* g, void* l) {
    __builtin_amdgcn_global_load_lds(
        (const __attribute__((address_space(1))) void*)g,
        (__attribute__((address_space(3))) void*)l,
        16, 0, 0);
}

// ---------------- transpose + fp32->bf16 cast:  src [E][R][C] f32 -> dst [E][C][R] bf16
__global__ __launch_bounds__(256) void transpose_cvt(const float* __restrict__ src,
                                                     unsigned short* __restrict__ dst,
                                                     int R, int C) {
    __shared__ float tile[32][33];
    int e = blockIdx.z;
    int c0 = blockIdx.x * 32;
    int r0 = blockIdx.y * 32;
    const float* s = src + (size_t)e * R * C;
    unsigned short* d = dst + (size_t)e * R * C;
    int tx = threadIdx.x, ty = threadIdx.y;   // 32 x 8
    #pragma unroll
    for (int i = 0; i < 4; i++)
        tile[ty + 8 * i][tx] = s[(size_t)(r0 + ty + 8 * i) * C + c0 + tx];
    __syncthreads();
    #pragma unroll
    for (int i = 0; i < 4; i++)
        d[(size_t)(c0 + ty + 8 * i) * R + r0 + tx] = f2bf(tile[tx][ty + 8 * i]);
}

// ---------------- gating: Wg held in registers (no LDS -> no bank conflicts), f64 accum
__global__ __launch_bounds__(256) void gate_kernel(const float* __restrict__ x,
                                                   const float* __restrict__ Wg,
                                                   const float* __restrict__ bg,
                                                   int* __restrict__ route,
                                                   float* __restrict__ pmax,
                                                   int* __restrict__ blockCounts) {
    __shared__ int cnt[NEXP];
    __shared__ float bgs[NEXP];
    int tid = threadIdx.x;
    if (tid < NEXP) { cnt[tid] = 0; bgs[tid] = bg[tid]; }
    __syncthreads();
    int wave = tid >> 6, lane = tid & 63;
    // per-lane copy of Wg rows [lane*8 .. lane*8+7]  ->  w[jj][e]
    float w[8][8];
    #pragma unroll
    for (int jj = 0; jj < 8; jj++) {
        float4 a = *(const float4*)(Wg + (size_t)(lane * 8 + jj) * NEXP);
        float4 b = *(const float4*)(Wg + (size_t)(lane * 8 + jj) * NEXP + 4);
        w[jj][0] = a.x; w[jj][1] = a.y; w[jj][2] = a.z; w[jj][3] = a.w;
        w[jj][4] = b.x; w[jj][5] = b.y; w[jj][6] = b.z; w[jj][7] = b.w;
    }
    int tbase = blockIdx.x * GB_TOK + wave * 16;
    for (int it = 0; it < 16; it++) {
        int t = tbase + it;
        float4 xa = *(const float4*)(x + (size_t)t * DDIM + lane * 8);
        float4 xb = *(const float4*)(x + (size_t)t * DDIM + lane * 8 + 4);
        float xs[8] = {xa.x, xa.y, xa.z, xa.w, xb.x, xb.y, xb.z, xb.w};
        double acc[NEXP];
        #pragma unroll
        for (int e = 0; e < NEXP; e++) acc[e] = 0.0;
        #pragma unroll
        for (int jj = 0; jj < 8; jj++) {
            double xv = (double)xs[jj];
            #pragma unroll
            for (int e = 0; e < NEXP; e++) acc[e] += xv * (double)w[jj][e];
        }
        #pragma unroll
        for (int off = 32; off > 0; off >>= 1) {
            #pragma unroll
            for (int e = 0; e < NEXP; e++) acc[e] += __shfl_down(acc[e], off);
        }
        if (lane == 0) {
            double l[NEXP];
            #pragma unroll
            for (int e = 0; e < NEXP; e++) l[e] = acc[e] + (double)bgs[e];
            int r = 0; double lm = l[0];
            #pragma unroll
            for (int e = 1; e < NEXP; e++) if (l[e] > lm) { lm = l[e]; r = e; }
            double s = 0.0;
            #pragma unroll
            for (int e = 0; e < NEXP; e++) s += exp(l[e] - lm);
            route[t] = r;
            pmax[t] = (float)(1.0 / s);
            atomicAdd(&cnt[r], 1);
        }
    }
    __syncthreads();
    if (tid < NEXP) blockCounts[blockIdx.x * NEXP + tid] = cnt[tid];
}

// ---------------- single-block scan -> stable counting-sort offsets + GEMM tile lists
__global__ __launch_bounds__(NGB) void scan_kernel(const int* __restrict__ blockCounts,
                                                   int* __restrict__ blockOffsets,
                                                   int* __restrict__ segPrefix,
                                                   int* __restrict__ tilePrefix) {
    __shared__ int sc[NGB][NEXP];
    __shared__ int base[NEXP + 1];
    int b = threadIdx.x;
    int c[NEXP];
    #pragma unroll
    for (int e = 0; e < NEXP; e++) { c[e] = blockCounts[b * NEXP + e]; sc[b][e] = c[e]; }
    __syncthreads();
    for (int off = 1; off < NGB; off <<= 1) {
        int t[NEXP];
        if (b >= off) {
            #pragma unroll
            for (int e = 0; e < NEXP; e++) t[e] = sc[b - off][e];
        }
        __syncthreads();
        if (b >= off) {
            #pragma unroll
            for (int e = 0; e < NEXP; e++) sc[b][e] += t[e];
        }
        __syncthreads();
    }
    if (b == 0) {
        int s = 0;
        #pragma unroll
        for (int e = 0; e < NEXP; e++) { base[e] = s; s += sc[NGB - 1][e]; }
        base[NEXP] = s;
        for (int e = 0; e <= NEXP; e++) segPrefix[e] = base[e];
        int tp = 0;
        tilePrefix[0] = 0;
        for (int e = 0; e < NEXP; e++) {
            tp += (sc[NGB - 1][e] + 127) / 128;
            tilePrefix[e + 1] = tp;
        }
    }
    __syncthreads();
    #pragma unroll
    for (int e = 0; e < NEXP; e++)
        blockOffsets[b * NEXP + e] = base[e] + sc[b][e] - c[e];
}

// ---------------- scatter: Xs[dst(t)] = bf16(x[t] * pmax[t]), expert-sorted stable order
__global__ __launch_bounds__(256) void scatter_kernel(const float* __restrict__ x,
                                                      const int* __restrict__ route,
                                                      const float* __restrict__ pmax,
                                                      const int* __restrict__ blockOffsets,
                                                      unsigned short* __restrict__ Xs) {
    __shared__ int dstL[GB_TOK];
    __shared__ float pmL[GB_TOK];
    int tid = threadIdx.x;
    int bb = blockIdx.x;
    if (tid < 64) {
        int t = bb * GB_TOK + tid;
        int r = route[t];
        unsigned long long ltmask = (tid == 0) ? 0ull : ((~0ull) >> (64 - tid));
        int rank = 0;
        #pragma unroll
        for (int e = 0; e < NEXP; e++) {
            unsigned long long m = __ballot(r == e);
            if (r == e) rank = __popcll(m & ltmask);
        }
        dstL[tid] = blockOffsets[bb * NEXP + r] + rank;
        pmL[tid] = pmax[t];
    }
    __syncthreads();
    int wave = tid >> 6, lane = tid & 63;
    for (int rr = 0; rr < 16; rr++) {
        int rowl = wave * 16 + rr;
        int t = bb * GB_TOK + rowl;
        float pm = pmL[rowl];
        const float4* xr = (const float4*)(x + (size_t)t * DDIM) + lane * 2;
        float4 a = xr[0], b = xr[1];
        union { short8_t v; unsigned short s[8]; } o;
        o.s[0] = f2bf(a.x * pm); o.s[1] = f2bf(a.y * pm);
        o.s[2] = f2bf(a.z * pm); o.s[3] = f2bf(a.w * pm);
        o.s[4] = f2bf(b.x * pm); o.s[5] = f2bf(b.y * pm);
        o.s[6] = f2bf(b.z * pm); o.s[7] = f2bf(b.w * pm);
        *(short8_t*)(Xs + (size_t)dstL[rowl] * DDIM + lane * 8) = o.v;
    }
}

// ---------------- segmented GEMM, BK=64 (two m97-layout 32-k panels), compact tile grid.
// A [TTOK][K] bf16, Bt [E][N][K] bf16. 128x128 tile, 4 waves, optional split-K via blockIdx.z.
template <bool RELU, bool BIAS, typename OutT>
__global__ __launch_bounds__(256) void gemm_seg(const unsigned short* __restrict__ A,
                                                const unsigned short* __restrict__ Bt,
                                                const float* __restrict__ bias,
                                                OutT* __restrict__ C,
                                                const int* __restrict__ segPrefix,
                                                const int* __restrict__ tilePrefix,
                                                int K, int N, int kLen) {
    int t = blockIdx.x;
    if (t >= tilePrefix[NEXP]) return;
    int e = 0;
    #pragma unroll
    for (int i = 1; i <= NEXP; i++) e += (t >= tilePrefix[i]) ? 1 : 0;
    // e is now index of expert owning tile t (tilePrefix[e] <= t < tilePrefix[e+1])
    int seg1 = segPrefix[e + 1];
    int m0 = segPrefix[e] + (t - tilePrefix[e]) * 128;
    int n0 = blockIdx.y * 128;
    int kc0 = blockIdx.z * kLen;
    C += (size_t)blockIdx.z * TTOK * N;   // split-K partial buffers

    // two 32-k panels, each [8 regions][16 rows][32 k] bf16 -> 8 KB per panel
    __shared__ unsigned short As[2 * 4096];
    __shared__ unsigned short Bs[2 * 4096];

    int tid = threadIdx.x, wave = tid >> 6, lane = tid & 63;
    const unsigned short* Bte = Bt + (size_t)e * N * K;

    int srow = lane >> 2;          // staging row within 16-row region
    int scol = (lane & 3) * 8;     // staging k-offset (8 bf16 = 16 B)

    f32x4_t acc[4][4];
    #pragma unroll
    for (int i = 0; i < 4; i++)
        #pragma unroll
        for (int j = 0; j < 4; j++) acc[i][j] = (f32x4_t){0.f, 0.f, 0.f, 0.f};

    int wm = (wave & 1) * 64;
    int wn = (wave >> 1) * 64;
    int frow = lane & 15;
    int fk = (lane >> 4) * 8;

    for (int kc = 0; kc < kLen; kc += 64) {
        int kg = kc0 + kc;
        #pragma unroll
        for (int p = 0; p < 2; p++) {
            #pragma unroll
            for (int i = 0; i < 2; i++) {
                int reg = wave * 2 + i;                 // 16-row region 0..7
                int arow = m0 + reg * 16 + srow;
                arow = arow < TTOK ? arow : TTOK - 1;   // clamp: masked at store
                gl_lds16(A + (size_t)arow * K + kg + p * 32 + scol, &As[p * 4096 + reg * 512]);
                int brow = n0 + reg * 16 + srow;
                gl_lds16(Bte + (size_t)brow * K + kg + p * 32 + scol, &Bs[p * 4096 + reg * 512]);
            }
        }
        __syncthreads();   // drains vmcnt -> LDS visible
        #pragma unroll
        for (int p = 0; p < 2; p++) {
            short8_t af[4], bfr[4];
            #pragma unroll
            for (int i = 0; i < 4; i++)
                af[i] = *(const short8_t*)&As[p * 4096 + (wm + i * 16 + frow) * 32 + fk];
            #pragma unroll
            for (int j = 0; j < 4; j++)
                bfr[j] = *(const short8_t*)&Bs[p * 4096 + (wn + j * 16 + frow) * 32 + fk];
            #pragma unroll
            for (int i = 0; i < 4; i++)
                #pragma unroll
                for (int j = 0; j < 4; j++)
                    acc[i][j] = __builtin_amdgcn_mfma_f32_16x16x32_bf16(af[i], bfr[j], acc[i][j], 0, 0, 0);
        }
        __syncthreads();   // all waves done reading before next overwrite
    }

    int quad = lane >> 4;
    int colb = lane & 15;
    #pragma unroll
    for (int i = 0; i < 4; i++) {
        #pragma unroll
        for (int j = 0; j < 4; j++) {
            int col = n0 + wn + j * 16 + colb;
            float bv = BIAS ? bias[(size_t)e * N + col] : 0.0f;
            #pragma unroll
            for (int r = 0; r < 4; r++) {
                int row = m0 + wm + i * 16 + quad * 4 + r;
                if (row < seg1) {
                    float v = acc[i][j][r] + bv;
                    if (RELU) v = fmaxf(v, 0.0f);
                    if constexpr (sizeof(OutT) == 2) {
                        C[(size_t)row * N + col] = (OutT)f2bf(v);
                    } else {
                        C[(size_t)row * N + col] = v;
                    }
                }
            }
        }
    }
}

// ---------------- split-K reduce: out = part0 + part1 + b2[expert(row)]
__global__ __launch_bounds__(256) void reduce_add(const float* __restrict__ part,
                                                  const float* __restrict__ b2,
                                                  const int* __restrict__ segPrefix,
                                                  float* __restrict__ out) {
    __shared__ int sp[NEXP + 1];
    if (threadIdx.x <= NEXP) sp[threadIdx.x] = segPrefix[threadIdx.x];
    __syncthreads();
    int wave = threadIdx.x >> 6, lane = threadIdx.x & 63;
    int row = blockIdx.x * 4 + wave;
    int e = 0;
    #pragma unroll
    for (int i = 1; i < NEXP; i++) e += (row >= sp[i]) ? 1 : 0;
    const float4* p0 = (const float4*)(part + (size_t)row * DDIM) + lane * 2;
    const float4* p1 = (const float4*)(part + (size_t)(TTOK + row) * DDIM) + lane * 2;
    const float4* bv = (const float4*)(b2 + (size_t)e * DDIM) + lane * 2;
    float4* o = (float4*)(out + (size_t)row * DDIM) + lane * 2;
    #pragma unroll
    for (int k = 0; k < 2; k++) {
        float4 a = p0[k], b = p1[k], c = bv[k];
        o[k] = make_float4(a.x + b.x + c.x, a.y + b.y + c.y,
                           a.z + b.z + c.z, a.w + b.w + c.w);
    }
}

extern "C" void kernel_launch(void* const* d_in, const int* in_sizes, int n_in,
                              void* d_out, int out_size, void* d_ws, size_t ws_size,
                              hipStream_t stream) {
    const float* x  = (const float*)d_in[0];
    const float* Wg = (const float*)d_in[1];
    const float* bg = (const float*)d_in[2];
    const float* W1 = (const float*)d_in[3];
    const float* b1 = (const float*)d_in[4];
    const float* W2 = (const float*)d_in[5];
    const float* b2 = (const float*)d_in[6];
    float* out = (float*)d_out;

    char* ws = (char*)d_ws;
    size_t off = 0;
    auto alloc = [&](size_t bytes) -> char* {
        char* p = ws + off;
        off += (bytes + 255) & ~(size_t)255;
        return p;
    };
    unsigned short* W1T = (unsigned short*)alloc((size_t)NEXP * DDIM * FFDIM * 2);  // [E][FF][D]
    unsigned short* W2T = (unsigned short*)alloc((size_t)NEXP * DDIM * FFDIM * 2);  // [E][D][FF]
    unsigned short* Xs  = (unsigned short*)alloc((size_t)TTOK * DDIM * 2);          // sorted tokens
    unsigned short* H   = (unsigned short*)alloc((size_t)TTOK * FFDIM * 2);         // hidden
    int*   route        = (int*)alloc((size_t)TTOK * 4);
    float* pmaxArr      = (float*)alloc((size_t)TTOK * 4);
    int*   blockCounts  = (int*)alloc((size_t)NGB * NEXP * 4);
    int*   blockOffsets = (int*)alloc((size_t)NGB * NEXP * 4);
    int*   segPrefix    = (int*)alloc((size_t)(NEXP + 1) * 4);
    int*   tilePrefix   = (int*)alloc((size_t)(NEXP + 1) * 4);
    size_t baseBytes = off;
    float* part = (float*)alloc((size_t)2 * TTOK * DDIM * 4);   // split-K partials (67 MB)
    bool doSplit = (off <= ws_size);   // ws_size is fixed per process -> same work every call
    if (!doSplit) off = baseBytes;

    // 1-2: weight transpose + bf16 cast
    transpose_cvt<<<dim3(FFDIM / 32, DDIM / 32, NEXP), dim3(32, 8), 0, stream>>>(W1, W1T, DDIM, FFDIM);
    transpose_cvt<<<dim3(DDIM / 32, FFDIM / 32, NEXP), dim3(32, 8), 0, stream>>>(W2, W2T, FFDIM, DDIM);
    // 3: gating
    gate_kernel<<<NGB, 256, 0, stream>>>(x, Wg, bg, route, pmaxArr, blockCounts);
    // 4: scan -> stable sort offsets + tile lists
    scan_kernel<<<1, NGB, 0, stream>>>(blockCounts, blockOffsets, segPrefix, tilePrefix);
    // 5: permute + scale + cast tokens
    scatter_kernel<<<NGB, 256, 0, stream>>>(x, route, pmaxArr, blockOffsets, Xs);
    // 6: H = relu(Xs @ W1[e] + b1[e])  (bf16), compact grid
    gemm_seg<true, true, unsigned short><<<dim3(MAXTILES, FFDIM / 128, 1), 256, 0, stream>>>(
        Xs, W1T, b1, H, segPrefix, tilePrefix, DDIM, FFDIM, DDIM);
    // 7: out = H @ W2[e] + b2[e]  (fp32, sorted order)
    if (doSplit) {
        gemm_seg<false, false, float><<<dim3(MAXTILES, DDIM / 128, 2), 256, 0, stream>>>(
            H, W2T, nullptr, part, segPrefix, tilePrefix, FFDIM, DDIM, FFDIM / 2);
        reduce_add<<<TTOK / 4, 256, 0, stream>>>(part, b2, segPrefix, out);
    } else {
        gemm_seg<false, true, float><<<dim3(MAXTILES, DDIM / 128, 1), 256, 0, stream>>>(
            H, W2T, b2, out, segPrefix, tilePrefix, FFDIM, DDIM, FFDIM);
    }
}